// Round 3
// baseline (10975.244 us; speedup 1.0000x reference)
//
#include <hip/hip_runtime.h>
#include <hip/hip_bf16.h>

// ---------------------------------------------------------------------------
// SA_NET: LSTM(4096 steps, H=512) + CNN branch + MLP head.
// Round 2: (a) seg-rotated LDS reads -> zero bank conflicts in the h-matvec,
// (b) asm-pinned register-resident W_hh (compiler was reloading from L2),
// (c) 2-deep pipelined LLC poll (halves detect latency).
// ---------------------------------------------------------------------------

#define HSZ   512
#define ESZ   300
#define NBLK  64      // LSTM blocks: block b owns h[8b..8b+7]

__device__ __forceinline__ float sigf(float x) {
    return 1.f / (1.f + __expf(-x));
}
__device__ __forceinline__ float tanh_fast(float x) {
    return 1.f - 2.f / (__expf(2.f * x) + 1.f);
}

#define LOAD_PK(p) __hip_atomic_load((p), __ATOMIC_RELAXED, __HIP_MEMORY_SCOPE_AGENT)

// ---------------------------------------------------------------------------
// Persistent LSTM. 64 blocks x 256 threads. Thread map: dot = tid>>3 (0..31)
// -> (jl = dot>>2, gate = dot&3); seg = tid&7 covers 64 h-elems of the dot.
// h exchanged via hpack[2][512]: 8-byte words = (step<<32)|f32bits, relaxed
// AGENT atomics (LLC-coherent) -> no fences anywhere.
// ---------------------------------------------------------------------------
template<bool USE_G>
__global__ __launch_bounds__(256, 1) void lstm_kernel(
    const float* __restrict__ inputs, const float* __restrict__ w_ih,
    const float* __restrict__ w_hh, const float* __restrict__ b_ih,
    const float* __restrict__ b_hh, const float* __restrict__ G,
    unsigned long long* hpack /*2*512*/, float* hmean /*512*/, int T)
{
    __shared__ float hlds[2][512];
    const int tid  = threadIdx.x;
    const int lane = tid & 63;
    const int wave = tid >> 6;
    const int dot  = tid >> 3;          // 0..31
    const int seg  = tid & 7;
    const int gate = dot & 3;
    const int jl   = dot >> 2;          // 0..7
    const int j    = blockIdx.x * 8 + jl;
    const int row  = gate * HSZ + j;    // row in w_hh / gate vector

    // --- register-resident recurrent weights, loaded in seg-rotated chunk
    // order so the per-step LDS reads are bank-conflict-free. ---
    float4 wh[16];
    int offs[16];                        // float4 index into hlds[p]
    {
        const float4* whp = (const float4*)(w_hh + (size_t)row * HSZ);
#pragma unroll
        for (int i = 0; i < 16; ++i) {
            int chunk = (i + seg) & 15;          // rotation within my segment
            offs[i] = seg * 16 + chunk;          // float4 units
            wh[i] = whp[seg * 16 + chunk];
        }
    }
    // Opaque-modify barrier: forbids rematerialization (reload-from-global)
    // of wh inside the step loop -> true VGPR residency.
#pragma unroll
    for (int i = 0; i < 16; ++i) {
        asm volatile("" : "+v"(wh[i].x), "+v"(wh[i].y),
                          "+v"(wh[i].z), "+v"(wh[i].w));
    }

    // fallback-only: register x-weights (seg 7 covers e=[260,300), first 20 zeroed)
    int base = 0;
    float wx[40];
    float bias = 0.f;
    if (!USE_G) {
        base = (seg == 7) ? 260 : seg * 40;
        const float* wxp = w_ih + (size_t)row * ESZ + base;
#pragma unroll
        for (int i = 0; i < 40; ++i) {
            bool valid = (seg < 7) || (i >= 20);
            wx[i] = valid ? wxp[i] : 0.f;
        }
        bias = b_ih[row] + b_hh[row];
    }

    float c = 0.f, hsum = 0.f;
    const int l0 = lane & 32;           // base lane of my half-wave (one j)
    const int j2 = blockIdx.x * 8 + wave * 2 + (lane >> 5);  // writer's h index

    for (int s = 1; s <= T; ++s) {
        const int t = s - 1;
        const int p = t & 1;

        // ---- pre-activation x-part (independent of h; issued before poll) ----
        float acc;
        if (USE_G) {
            acc = (seg == 0) ? G[(size_t)t * (4 * HSZ) + row] : 0.f;
        } else {
            acc = (seg == 0) ? bias : 0.f;
            const float4* xp4 = (const float4*)(inputs + (size_t)t * ESZ + base);
#pragma unroll
            for (int i4 = 0; i4 < 10; ++i4) {
                float4 x4 = xp4[i4];
                acc += wx[i4 * 4 + 0] * x4.x + wx[i4 * 4 + 1] * x4.y +
                       wx[i4 * 4 + 2] * x4.z + wx[i4 * 4 + 3] * x4.w;
            }
        }

        // ---- 2-deep pipelined poll of h_{s-1}: slot p, tag t ----
        {
            unsigned long long* w0p = hpack + (size_t)p * HSZ + tid;
            unsigned long long* w1p = w0p + 256;
            const unsigned tg = (unsigned)t;
            unsigned long long a0 = LOAD_PK(w0p), a1 = LOAD_PK(w1p);
            unsigned long long b0 = LOAD_PK(w0p), b1 = LOAD_PK(w1p);
            unsigned long long v0, v1;
            while (true) {
                if ((unsigned)(a0 >> 32) == tg && (unsigned)(a1 >> 32) == tg) {
                    v0 = a0; v1 = a1; break;
                }
                a0 = LOAD_PK(w0p); a1 = LOAD_PK(w1p);
                if ((unsigned)(b0 >> 32) == tg && (unsigned)(b1 >> 32) == tg) {
                    v0 = b0; v1 = b1; break;
                }
                b0 = LOAD_PK(w0p); b1 = LOAD_PK(w1p);
            }
            union { unsigned u; float f; } c0, c1;
            c0.u = (unsigned)v0; c1.u = (unsigned)v1;
            hlds[p][tid]       = c0.f;
            hlds[p][tid + 256] = c1.f;
        }
        __syncthreads();   // single barrier per step (hlds is parity-buffered)

        // ---- h-matvec from LDS (rotated chunks -> conflict-free) ----
        {
            const float4* hp = (const float4*)(&hlds[p][0]);
#pragma unroll
            for (int i = 0; i < 16; ++i) {
                float4 h4 = hp[offs[i]];
                acc += wh[i].x * h4.x + wh[i].y * h4.y +
                       wh[i].z * h4.z + wh[i].w * h4.w;
            }
        }
        // reduce across the 8 seg lanes
        acc += __shfl_xor(acc, 4, 64);
        acc += __shfl_xor(acc, 2, 64);
        acc += __shfl_xor(acc, 1, 64);

        // gather the 4 gates of my half-wave's j
        float gi = __shfl(acc, l0 + 0,  64);
        float gf = __shfl(acc, l0 + 8,  64);
        float gg = __shfl(acc, l0 + 16, 64);
        float go = __shfl(acc, l0 + 24, 64);

        float is = sigf(gi), fs = sigf(gf), os = sigf(go);
        float gt = tanh_fast(gg);
        c = fs * c + is * gt;
        float h = os * tanh_fast(c);

        if ((lane & 31) == 0) {
            union { float f; unsigned u; } hv; hv.f = h;
            unsigned long long pk =
                ((unsigned long long)(unsigned)s << 32) | (unsigned long long)hv.u;
            __hip_atomic_store(&hpack[(size_t)(s & 1) * HSZ + j2], pk,
                               __ATOMIC_RELAXED, __HIP_MEMORY_SCOPE_AGENT);
            hsum += h;
        }
    }

    if ((lane & 31) == 0)
        hmean[j2] = hsum * (1.f / (float)T);
}

// ---------------------------------------------------------------------------
// G = inputs[M,K] * w_ih[N,K]^T + (b_ih+b_hh)  — 64x64 tile, 4x4/thread,
// float4 global loads.
// ---------------------------------------------------------------------------
__global__ __launch_bounds__(256) void gemm_g(
    const float* __restrict__ A, const float* __restrict__ B,
    const float* __restrict__ bi, const float* __restrict__ bh,
    float* __restrict__ C, int M, int N, int K)
{
    __shared__ float As[16][65];
    __shared__ float Bs[16][65];
    const int tid = threadIdx.x;
    const int m0 = blockIdx.y * 64, n0 = blockIdx.x * 64;
    const int tm = (tid >> 4) * 4, tn = (tid & 15) * 4;
    const int lr = tid >> 2;          // 0..63 tile row
    const int lk = (tid & 3) * 4;     // 0,4,8,12
    float acc[4][4] = {};

    for (int kk = 0; kk < K; kk += 16) {
        int k0 = kk + lk;
        float4 av = {0.f, 0.f, 0.f, 0.f}, bv = {0.f, 0.f, 0.f, 0.f};
        if (m0 + lr < M) {
            const float* ap = A + (size_t)(m0 + lr) * K;
            if (k0 + 3 < K) av = *(const float4*)(ap + k0);
            else {
                float tmp[4];
#pragma unroll
                for (int e = 0; e < 4; ++e) tmp[e] = (k0 + e < K) ? ap[k0 + e] : 0.f;
                av.x = tmp[0]; av.y = tmp[1]; av.z = tmp[2]; av.w = tmp[3];
            }
        }
        {
            const float* bp = B + (size_t)(n0 + lr) * K;
            if (k0 + 3 < K) bv = *(const float4*)(bp + k0);
            else {
                float tmp[4];
#pragma unroll
                for (int e = 0; e < 4; ++e) tmp[e] = (k0 + e < K) ? bp[k0 + e] : 0.f;
                bv.x = tmp[0]; bv.y = tmp[1]; bv.z = tmp[2]; bv.w = tmp[3];
            }
        }
        As[lk + 0][lr] = av.x; As[lk + 1][lr] = av.y;
        As[lk + 2][lr] = av.z; As[lk + 3][lr] = av.w;
        Bs[lk + 0][lr] = bv.x; Bs[lk + 1][lr] = bv.y;
        Bs[lk + 2][lr] = bv.z; Bs[lk + 3][lr] = bv.w;
        __syncthreads();
#pragma unroll
        for (int k2 = 0; k2 < 16; ++k2) {
            float a0 = As[k2][tm], a1 = As[k2][tm + 1],
                  a2 = As[k2][tm + 2], a3 = As[k2][tm + 3];
            float b0 = Bs[k2][tn], b1 = Bs[k2][tn + 1],
                  b2 = Bs[k2][tn + 2], b3 = Bs[k2][tn + 3];
            acc[0][0] += a0 * b0; acc[0][1] += a0 * b1;
            acc[0][2] += a0 * b2; acc[0][3] += a0 * b3;
            acc[1][0] += a1 * b0; acc[1][1] += a1 * b1;
            acc[1][2] += a1 * b2; acc[1][3] += a1 * b3;
            acc[2][0] += a2 * b0; acc[2][1] += a2 * b1;
            acc[2][2] += a2 * b2; acc[2][3] += a2 * b3;
            acc[3][0] += a3 * b0; acc[3][1] += a3 * b1;
            acc[3][2] += a3 * b2; acc[3][3] += a3 * b3;
        }
        __syncthreads();
    }
#pragma unroll
    for (int i = 0; i < 4; ++i) {
        int m = m0 + tm + i;
        if (m >= M) break;
#pragma unroll
        for (int jj = 0; jj < 4; ++jj) {
            int n = n0 + tn + jj;
            C[(size_t)m * N + n] = acc[i][jj] + bi[n] + bh[n];
        }
    }
}

// ---------------------------------------------------------------------------
// Generic tiled fp32 GEMM for CNN: C[M,N] = A[M,K]*B[N,K]^T + bias[n]
// ---------------------------------------------------------------------------
__global__ __launch_bounds__(256) void gemm32(
    const float* __restrict__ A, const float* __restrict__ B,
    const float* __restrict__ bias, float* __restrict__ C,
    int M, int N, int K)
{
    __shared__ float As[32][33];
    __shared__ float Bs[32][33];
    const int tid = threadIdx.x;
    const int m0 = blockIdx.y * 32, n0 = blockIdx.x * 32;
    const int tn = (tid & 15) * 2, tm = (tid >> 4) * 2;
    float a00 = 0, a01 = 0, a10 = 0, a11 = 0;

    for (int kk = 0; kk < K; kk += 32) {
        const int k = tid & 31, r = tid >> 5;
#pragma unroll
        for (int jj = 0; jj < 4; ++jj) {
            int m = r + jj * 8;
            As[k][m] = (kk + k < K && m0 + m < M)
                         ? A[(size_t)(m0 + m) * K + kk + k] : 0.f;
            Bs[k][m] = (kk + k < K && n0 + m < N)
                         ? B[(size_t)(n0 + m) * K + kk + k] : 0.f;
        }
        __syncthreads();
#pragma unroll
        for (int k2 = 0; k2 < 32; ++k2) {
            float x0 = As[k2][tm], x1 = As[k2][tm + 1];
            float y0 = Bs[k2][tn], y1 = Bs[k2][tn + 1];
            a00 += x0 * y0; a01 += x0 * y1;
            a10 += x1 * y0; a11 += x1 * y1;
        }
        __syncthreads();
    }
    const int m = m0 + tm, n = n0 + tn;
    if (m < M) {
        if (n     < N) C[(size_t)m * N + n]     = a00 + bias[n];
        if (n + 1 < N) C[(size_t)m * N + n + 1] = a01 + bias[n + 1];
    }
    if (m + 1 < M) {
        if (n     < N) C[(size_t)(m + 1) * N + n]     = a10 + bias[n];
        if (n + 1 < N) C[(size_t)(m + 1) * N + n + 1] = a11 + bias[n + 1];
    }
}

// im2col for conv1: X[t*2100 + dt*300 + e] = in[(t+dt-3)*300+e] (zero pad)
__global__ void im2col1(const float* __restrict__ in, float* __restrict__ X)
{
    int idx = blockIdx.x * 256 + threadIdx.x;
    if (idx >= 512 * 2100) return;
    int t = idx / 2100, k = idx - t * 2100;
    int dt = k / 300, e = k - dt * 300;
    int tt = t + dt - 3;
    X[idx] = (tt >= 0 && tt < 512) ? in[tt * 300 + e] : 0.f;
}

// generic 1d im2col: X[t*(Cin*KW) + c*KW + dk] = S[c*L + t+dk-pad] (zero pad)
__global__ void im2colN(const float* __restrict__ S, float* __restrict__ X,
                        int L, int Cin, int KW, int pad, int total)
{
    int idx = blockIdx.x * 256 + threadIdx.x;
    if (idx >= total) return;
    int KC = Cin * KW;
    int t = idx / KC, r = idx - t * KC;
    int c = r / KW, dk = r - c * KW;
    int tt = t + dk - pad;
    X[idx] = (tt >= 0 && tt < L) ? S[c * L + tt] : 0.f;
}

// X4[t*256+c] = s3[c*64+t]
__global__ void transpose4(const float* __restrict__ S, float* __restrict__ X)
{
    int idx = blockIdx.x * 256 + threadIdx.x;
    if (idx >= 64 * 256) return;
    int t = idx >> 8, c = idx & 255;
    X[idx] = S[c * 64 + t];
}

// S[c*LP+tp] = sig(max(C[(2tp)*Cch+c], C[(2tp+1)*Cch+c]))
__global__ void poolsig(const float* __restrict__ Cin_, float* __restrict__ S,
                        int Cch, int LP)
{
    int idx = blockIdx.x * 256 + threadIdx.x;
    if (idx >= Cch * LP) return;
    int c = idx / LP, tp = idx - c * LP;
    float a = Cin_[(2 * tp) * Cch + c];
    float b = Cin_[(2 * tp + 1) * Cch + c];
    S[idx] = sigf(fmaxf(a, b));
}

// y[o*64+t] = sig(C4[t*16+o])
__global__ void sigy(const float* __restrict__ C4, float* __restrict__ y)
{
    int idx = blockIdx.x * 256 + threadIdx.x;
    if (idx >= 1024) return;
    int o = idx >> 6, t = idx & 63;
    y[idx] = sigf(C4[t * 16 + o]);
}

// fc1: 128 blocks x 64 lanes; x = [hmean(512) | y(1024)]
__global__ void fc1_kernel(const float* __restrict__ hmean,
                           const float* __restrict__ y,
                           const float* __restrict__ w,
                           const float* __restrict__ b,
                           float* __restrict__ out)
{
    int k = blockIdx.x, lane = threadIdx.x;
    float a = 0.f;
    for (int i = lane; i < 1536; i += 64) {
        float xv = (i < 512) ? hmean[i] : y[i - 512];
        a += xv * w[k * 1536 + i];
    }
#pragma unroll
    for (int off = 32; off; off >>= 1) a += __shfl_xor(a, off, 64);
    if (lane == 0) out[k] = sigf(a + b[k]);
}

// fc2 (32x128) + fc3 (1x32), single block
__global__ void head_kernel(const float* __restrict__ x2,
                            const float* __restrict__ w2, const float* __restrict__ b2,
                            const float* __restrict__ w3, const float* __restrict__ b3,
                            float* __restrict__ out)
{
    __shared__ float x3[32];
    int lane = threadIdx.x;
    if (lane < 32) {
        float a = 0.f;
        for (int i = 0; i < 128; ++i) a += x2[i] * w2[lane * 128 + i];
        x3[lane] = sigf(a + b2[lane]);
    }
    __syncthreads();
    if (lane == 0) {
        float a = 0.f;
        for (int i = 0; i < 32; ++i) a += x3[i] * w3[i];
        out[0] = sigf(a + b3[0]);
    }
}

extern "C" void kernel_launch(void* const* d_in, const int* in_sizes, int n_in,
                              void* d_out, int out_size, void* d_ws, size_t ws_size,
                              hipStream_t stream)
{
    const float* inputs = (const float*)d_in[0];
    const float* w_ih   = (const float*)d_in[1];
    const float* w_hh   = (const float*)d_in[2];
    const float* b_ih   = (const float*)d_in[3];
    const float* b_hh   = (const float*)d_in[4];
    const float* c1w    = (const float*)d_in[5];
    const float* c1b    = (const float*)d_in[6];
    const float* c2w    = (const float*)d_in[7];
    const float* c2b    = (const float*)d_in[8];
    const float* c3w    = (const float*)d_in[9];
    const float* c3b    = (const float*)d_in[10];
    const float* c4w    = (const float*)d_in[11];
    const float* c4b    = (const float*)d_in[12];
    const float* fc1w   = (const float*)d_in[13];
    const float* fc1b   = (const float*)d_in[14];
    const float* fc2w   = (const float*)d_in[15];
    const float* fc2b   = (const float*)d_in[16];
    const float* fc3w   = (const float*)d_in[17];
    const float* fc3b   = (const float*)d_in[18];
    float* out = (float*)d_out;
    const int T = in_sizes[0] / ESZ;   // 4096

    // ---- workspace layout (floats) ----
    float* p = (float*)d_ws;
    unsigned long long* hpack = (unsigned long long*)p;  // 2*512 u64 = 2048 f
    float* hmean = p + 2048;                  // 512
    float* X1 = p + 2560;                     // 512*2100 = 1075200
    float* C1 = X1 + 1075200;                 // 512*256  = 131072
    float* s1 = C1 + 131072;                  // 256*256  = 65536
    float* X2 = s1 + 65536;                   // 256*1280 = 327680
    float* C2 = X2 + 327680;                  // 256*64   = 16384
    float* s2 = C2 + 16384;                   // 64*128   = 8192
    float* X3 = s2 + 8192;                    // 128*192  = 24576
    float* C3 = X3 + 24576;                   // 128*256  = 32768
    float* s3 = C3 + 32768;                   // 256*64   = 16384
    float* X4 = s3 + 16384;                   // 64*256   = 16384
    float* C4 = X4 + 16384;                   // 64*16    = 1024
    float* yb = C4 + 1024;                    // 1024
    float* x2 = yb + 1024;                    // 128
    float* G  = x2 + 128;                     // T*2048 floats (32 MB @ T=4096)
    const size_t need_bytes = ((size_t)(x2 + 128 - p) + (size_t)T * 2048) * 4;
    const bool use_g = ws_size >= need_bytes;

    // zero hpack (h_0 = 0, tag 0) — re-run/replay safe
    hipMemsetAsync(p, 0, 2048 * sizeof(float), stream);

    if (use_g) {
        // G = inputs * w_ih^T + b_ih + b_hh   [T x 2048]
        gemm_g<<<dim3(2048 / 64, (T + 63) / 64), 256, 0, stream>>>(
            inputs, w_ih, b_ih, b_hh, G, T, 2048, ESZ);
        lstm_kernel<true><<<NBLK, 256, 0, stream>>>(
            inputs, w_ih, w_hh, b_ih, b_hh, G, hpack, hmean, T);
    } else {
        lstm_kernel<false><<<NBLK, 256, 0, stream>>>(
            inputs, w_ih, w_hh, b_ih, b_hh, (const float*)nullptr,
            hpack, hmean, T);
    }

    // ---- CNN branch ----
    im2col1<<<4200, 256, 0, stream>>>(inputs, X1);
    gemm32<<<dim3(8, 16), 256, 0, stream>>>(X1, c1w, c1b, C1, 512, 256, 2100);
    poolsig<<<256, 256, 0, stream>>>(C1, s1, 256, 256);

    im2colN<<<1280, 256, 0, stream>>>(s1, X2, 256, 256, 5, 2, 256 * 1280);
    gemm32<<<dim3(2, 8), 256, 0, stream>>>(X2, c2w, c2b, C2, 256, 64, 1280);
    poolsig<<<32, 256, 0, stream>>>(C2, s2, 64, 128);

    im2colN<<<96, 256, 0, stream>>>(s2, X3, 128, 64, 3, 1, 128 * 192);
    gemm32<<<dim3(8, 4), 256, 0, stream>>>(X3, c3w, c3b, C3, 128, 256, 192);
    poolsig<<<64, 256, 0, stream>>>(C3, s3, 256, 64);

    transpose4<<<64, 256, 0, stream>>>(s3, X4);
    gemm32<<<dim3(1, 2), 256, 0, stream>>>(X4, c4w, c4b, C4, 64, 16, 256);
    sigy<<<4, 256, 0, stream>>>(C4, yb);

    // ---- MLP head ----
    fc1_kernel<<<128, 64, 0, stream>>>(hmean, yb, fc1w, fc1b, x2);
    head_kernel<<<1, 64, 0, stream>>>(x2, fc2w, fc2b, fc3w, fc3b, out);
}